// Round 18
// baseline (438.003 us; speedup 1.0000x reference)
//
#include <hip/hip_runtime.h>
#include <math.h>

#define B_ROWS 2048
#define D_K    2048
#define DKB    1024             // bytes per row at fp4 (0.5 B/elem)
#define N_CLS  50257
#define BM     128
#define BN     128
#define BKB    64               // K-BYTES per step = 128 elements
#define NT     16               // 2048 / 128 elements
#define GM     16               // 2048/128 m-tiles
#define GN     393              // ceil(50257/128) n-tiles
#define N_PAD  (GN * BN)        // 50304
#define NWG    (GM * GN)        // 6288 = 8*786 (bijective XCD swizzle)

// LDS: B-only TRIPLE buffer, 8KB each (distance-2 prefetch, counted vmcnt).
// Buffer b at b*8192: B [128 rows][64 B] fp4. 16-B slot swizzle per row:
// position p = content_slot ^ ((row>>1)&3) (verified conflict-free R16/R17).
// Stats (3KB) overlay buffer 0 after the K-loop's final barrier.
#define BUFB   8192

typedef __attribute__((ext_vector_type(4))) int   i32x4;
typedef __attribute__((ext_vector_type(8))) int   i32x8;
typedef __attribute__((ext_vector_type(4))) float f32x4;

typedef __attribute__((address_space(1))) const void as1cv;
typedef __attribute__((address_space(3))) void       as3v;

__device__ __forceinline__ void glds16(const void* g, void* l) {
  __builtin_amdgcn_global_load_lds((as1cv*)g, (as3v*)l, 16, 0, 0);
}

// ---- fp32 -> fp4 e2m1 (RNE on the 8-level grid), returns 4-bit code ----
__device__ __forceinline__ unsigned int q4(float x) {
  const unsigned int s = (x < 0.f) ? 8u : 0u;
  const float a = fabsf(x);
  unsigned int c;
  if      (a < 0.25f) c = 0;
  else if (a < 0.75f) c = 1;
  else if (a < 1.25f) c = 2;
  else if (a < 1.75f) c = 3;
  else if (a < 2.5f)  c = 4;
  else if (a < 3.5f)  c = 5;
  else if (a < 5.0f)  c = 6;
  else                c = 7;
  return s | c;
}

// ---------- W: fp32 -> fp4, scaled x128, zero-padded to N_PAD rows ----------
__global__ void conv_w_q4(const float* __restrict__ W, unsigned char* __restrict__ Wq) {
  const size_t NU = (size_t)N_PAD * D_K / 16;
  const size_t stride = (size_t)gridDim.x * blockDim.x;
  for (size_t u = (size_t)blockIdx.x * blockDim.x + threadIdx.x; u < NU; u += stride) {
    const size_t e = u * 16;
    unsigned long long pk = 0ull;
    if ((e >> 11) < (size_t)N_CLS) {
#pragma unroll
      for (int g = 0; g < 4; ++g) {
        const float4 a = *(const float4*)(W + e + g * 4);
        pk |= (unsigned long long)q4(a.x * 128.0f) << (16 * g + 0);
        pk |= (unsigned long long)q4(a.y * 128.0f) << (16 * g + 4);
        pk |= (unsigned long long)q4(a.z * 128.0f) << (16 * g + 8);
        pk |= (unsigned long long)q4(a.w * 128.0f) << (16 * g + 12);
      }
    }
    *(unsigned long long*)(Wq + u * 8) = pk;
  }
}

// ---------- E: fp32 -> fp4 in FRAGMENT-MAJOR layout ----------
// A-fragment (16-row block fr, K-step t) is contiguous 1KB: lane l =
// kchunk*16 + (row&15) holds that row's 16 bytes (32 elements) of chunk kchunk.
// dst = ((R>>4)*NT + t)*1024 + ((kc*16 + (R&15))*16) + ((k0&31)>>1)
__global__ void conv_e_q4(const float* __restrict__ E, unsigned char* __restrict__ EqT) {
  const size_t NU = (size_t)B_ROWS * D_K / 16;   // 16 elements (8 bytes) per unit
  const size_t stride = (size_t)gridDim.x * blockDim.x;
  for (size_t u = (size_t)blockIdx.x * blockDim.x + threadIdx.x; u < NU; u += stride) {
    const int R  = (int)(u >> 7);                // row (128 units per row)
    const int k0 = (int)(u & 127) * 16;          // first element index
    const float* src = E + (size_t)R * D_K + k0;
    unsigned long long pk = 0ull;
#pragma unroll
    for (int g = 0; g < 4; ++g) {
      const float4 a = *(const float4*)(src + g * 4);
      pk |= (unsigned long long)q4(a.x) << (16 * g + 0);
      pk |= (unsigned long long)q4(a.y) << (16 * g + 4);
      pk |= (unsigned long long)q4(a.z) << (16 * g + 8);
      pk |= (unsigned long long)q4(a.w) << (16 * g + 12);
    }
    const int t  = k0 >> 7;
    const int kc = (k0 & 127) >> 5;
    const int b  = (k0 & 31) >> 1;               // 0 or 8
    const size_t dst = ((size_t)(R >> 4) * NT + t) * 1024
                     + (size_t)(kc * 16 + (R & 15)) * 16 + b;
    *(unsigned long long*)(EqT + dst) = pk;
  }
}

// ---------- fused MX-fp4 GEMM + per-tile row stats ----------
// 128x128 tile, 4 waves (2x2), per-wave 64x64 via 4x4 mfma_scale 16x16x128 fp4.
// A: direct global->VGPR from fragment-major EqT (L1-resident, reg-dbuffered).
// B: LDS 3-buffer, distance-2 glds16, counted vmcnt. f32x4 acc (no-spill profile).
__global__ __launch_bounds__(256) void gemm_ce(
    const unsigned char* __restrict__ EqT,
    const unsigned char* __restrict__ Wq,
    const int* __restrict__ labels,
    float* __restrict__ pm, float* __restrict__ ps, float* __restrict__ pt,
    float* __restrict__ ly)
{
  __shared__ __align__(16) char lds[3 * BUFB];
  // stats overlay (live only after the K-loop's final barrier):
  float (*s_m)[2] = (float (*)[2])(lds);
  float (*s_s)[2] = (float (*)[2])(lds + 1024);
  float (*s_t)[2] = (float (*)[2])(lds + 2048);

  const int tid  = threadIdx.x;
  const int wid  = tid >> 6;
  const int lane = tid & 63;
  const int wm   = wid >> 1;       // 0..1 -> 64-row block
  const int wn   = wid & 1;        // 0..1 -> 64-col block
  const int l16  = lane & 15;
  const int lhi  = lane >> 4;      // 0..3 -> 32-element k-chunk

  // XCD-aware bijective swizzle (NWG = 8*786)
  const int bid     = blockIdx.x;
  const int logical = (bid & 7) * (NWG / 8) + (bid >> 3);
  const int n_tile  = logical / GM;   // 16 consecutive logicals share B panel
  const int m_tile  = logical % GM;

  // ---- B staging: thread t, part q=0..1 -> dest byte q*4096 + t*16
  //      row = q*64 + (t>>2); slot position = t&3
  //      content slot = (t&3) ^ ((row>>1)&3) = (t&3) ^ ((t>>3)&3)
  const int gsw  = (((tid & 3) ^ ((tid >> 3) & 3)) << 4);
  const int srow = tid >> 2;
  const unsigned char* Bg = Wq + (size_t)(n_tile * BN + srow) * DKB + gsw;
  const int sdst = tid * 16;
  // +q -> +64 rows = +65536 B global; +K-step -> +64 B

  // ---- B fragment LDS offsets: row R = wn*64 + fj*16 + l16, slot lhi,
  //      position = lhi ^ ((R>>1)&3) = lhi ^ ((l16>>1)&3)
  const int rmsk = (l16 >> 1) & 3;
  const int psw  = (lhi ^ rmsk) << 4;
  int offB[4];
#pragma unroll
  for (int fj = 0; fj < 4; ++fj)
    offB[fj] = (wn * 64 + fj * 16 + l16) * 64 + psw;

  // ---- A fragment global base (fragment-major EqT): frag-row index
  //      fridx = m_tile*8 + wm*4 + fi; addr = (fridx*NT + t)*1024 + lane*16
  const unsigned char* Ab = EqT
      + ((size_t)(m_tile * 8 + wm * 4) * NT) * 1024 + (size_t)lane * 16;
  // fa[fi] at step t: Ab + (fi*NT + t)*1024

  f32x4 acc[4][4] = {};

#define STAGE_B(BUF, TT)                                                   \
  do {                                                                     \
    const unsigned char* _b = Bg + (size_t)(TT) * BKB;                     \
    char* _d = lds + (BUF) * BUFB + sdst;                                  \
    glds16(_b,         _d);                                                \
    glds16(_b + 65536, _d + 4096);                                         \
  } while (0)

#define LOADA(DST, TT)                                                     \
  do {                                                                     \
    _Pragma("unroll")                                                      \
    for (int fi = 0; fi < 4; ++fi)                                         \
      DST[fi] = *(const i32x4*)(Ab + ((size_t)(fi * NT + (TT))) * 1024);   \
  } while (0)

  i32x4 faN[4];
  // prologue: stage B(0),B(1); load A(0); drain B(0) only (rest stays in flight)
  STAGE_B(0, 0);
  STAGE_B(1, 1);
  LOADA(faN, 0);
  asm volatile("s_waitcnt vmcnt(6)" ::: "memory");
  __builtin_amdgcn_sched_barrier(0);
  __builtin_amdgcn_s_barrier();
  __builtin_amdgcn_sched_barrier(0);

#pragma unroll
  for (int t = 0; t < NT; ++t) {
    const char* Rb = lds + (t % 3) * BUFB;

    i32x4 faC[4];
#pragma unroll
    for (int fi = 0; fi < 4; ++fi) faC[fi] = faN[fi];
    if (t < NT - 1) LOADA(faN, t + 1);          // A reg-prefetch (VMEM)
    if (t < NT - 2) STAGE_B((t + 2) % 3, t + 2); // B distance-2 prefetch

    i32x4 fbC[4];
#pragma unroll
    for (int fj = 0; fj < 4; ++fj)
      fbC[fj] = *(const i32x4*)(Rb + offB[fj]);

    __builtin_amdgcn_s_setprio(1);
#pragma unroll
    for (int fi = 0; fi < 4; ++fi) {
      i32x8 fa;
      fa[0] = faC[fi][0]; fa[1] = faC[fi][1]; fa[2] = faC[fi][2]; fa[3] = faC[fi][3];
      fa[4] = 0; fa[5] = 0; fa[6] = 0; fa[7] = 0;
#pragma unroll
      for (int fj = 0; fj < 4; ++fj) {
        i32x8 fb;
        fb[0] = fbC[fj][0]; fb[1] = fbC[fj][1]; fb[2] = fbC[fj][2]; fb[3] = fbC[fj][3];
        fb[4] = 0; fb[5] = 0; fb[6] = 0; fb[7] = 0;
        acc[fi][fj] = __builtin_amdgcn_mfma_scale_f32_16x16x128_f8f6f4(
            fa, fb, acc[fi][fj], 4, 4,               // cbsz=4, blgp=4 (e2m1)
            0, 0x7F7F7F7F, 0, 0x7F7F7F7F);           // uniform scales = 1.0
      }
    }
    __builtin_amdgcn_s_setprio(0);

    // end of step: drain through B(t+1) (oldest); keep A(t+1)+B(t+2) in flight.
    if (t < NT - 2)       asm volatile("s_waitcnt vmcnt(6)" ::: "memory");
    else if (t == NT - 2) asm volatile("s_waitcnt vmcnt(4)" ::: "memory");
    else                  asm volatile("s_waitcnt vmcnt(0)" ::: "memory");
    __builtin_amdgcn_sched_barrier(0);
    __builtin_amdgcn_s_barrier();
    __builtin_amdgcn_sched_barrier(0);
  }
#undef STAGE_B
#undef LOADA

  // ---------- epilogue: per-row (max, sumexp, sum) + label gather ----------
  // C/D 16x16: col = lane&15, row = (lane>>4)*4 + reg  [verified R9/R10/R16]
  const float inv = 0.0078125f;   // 1/128 (undo W pre-scale)
  const int row_base = m_tile * BM;
  const int col_base = n_tile * BN + wn * 64;

#pragma unroll
  for (int fi = 0; fi < 4; ++fi) {
#pragma unroll
    for (int r = 0; r < 4; ++r) {
      const int rt  = wm * 64 + fi * 16 + lhi * 4 + r;
      const int row = row_base + rt;
      const int lab = labels[row];
      const int rel = lab - col_base - l16;
#pragma unroll
      for (int fj = 0; fj < 4; ++fj) {
        if (rel == fj * 16) ly[row] = acc[fi][fj][r] * inv;   // static acc index
      }

      float mx = -INFINITY, sm = 0.f;
#pragma unroll
      for (int fj = 0; fj < 4; ++fj) {
        const bool v = (col_base + fj * 16 + l16) < N_CLS;
        const float x = acc[fi][fj][r] * inv;
        if (v) { mx = fmaxf(mx, x); sm += x; }
      }
#pragma unroll
      for (int d = 1; d < 16; d <<= 1) {
        mx = fmaxf(mx, __shfl_xor(mx, d));
        sm += __shfl_xor(sm, d);
      }
      float se = 0.f;
#pragma unroll
      for (int fj = 0; fj < 4; ++fj) {
        const bool v = (col_base + fj * 16 + l16) < N_CLS;
        if (v) se += __expf(acc[fi][fj][r] * inv - mx);
      }
#pragma unroll
      for (int d = 1; d < 16; d <<= 1) se += __shfl_xor(se, d);

      if (l16 == 0) { s_m[rt][wn] = mx; s_s[rt][wn] = se; s_t[rt][wn] = sm; }
    }
  }
  __syncthreads();
  if (tid < BM) {
    const float m0 = s_m[tid][0], m1 = s_m[tid][1];
    const float M = fmaxf(m0, m1);
    const float S = s_s[tid][0] * __expf(m0 - M) + s_s[tid][1] * __expf(m1 - M);
    const float T = s_t[tid][0] + s_t[tid][1];
    const size_t o = (size_t)n_tile * B_ROWS + row_base + tid;
    pm[o] = M; ps[o] = S; pt[o] = T;
  }
}

// ---------- final combine: GN partials per row -> loss ----------
__global__ void ce_reduce(const float* __restrict__ pm, const float* __restrict__ ps,
                          const float* __restrict__ pt, const float* __restrict__ ly,
                          float* __restrict__ out)
{
  const int tid = threadIdx.x;
  const int row = blockIdx.x * blockDim.x + tid;
  float M = -INFINITY, S = 0.f, T = 0.f;
  for (int nt = 0; nt < GN; ++nt) {
    const size_t o = (size_t)nt * B_ROWS + row;
    const float m = pm[o], s = ps[o], t = pt[o];
    const float Mn = fmaxf(M, m);
    S = S * __expf(M - Mn) + s * __expf(m - Mn);
    M = Mn;
    T += t;
  }
  const float lse = M + logf(S);
  float per = lse - 0.9f * ly[row] - 0.1f * (T * (1.0f / (float)N_CLS));
#pragma unroll
  for (int d = 1; d < 64; d <<= 1) per += __shfl_xor(per, d);
  __shared__ float red[4];
  if ((tid & 63) == 0) red[tid >> 6] = per;
  __syncthreads();
  if (tid == 0)
    atomicAdd(out, (red[0] + red[1] + red[2] + red[3]) * (1.0f / B_ROWS));
}

extern "C" void kernel_launch(void* const* d_in, const int* in_sizes, int n_in,
                              void* d_out, int out_size, void* d_ws, size_t ws_size,
                              hipStream_t stream)
{
  const float* E      = (const float*)d_in[0];
  const int*   labels = (const int*)  d_in[1];
  const float* W      = (const float*)d_in[2];
  float* out = (float*)d_out;

  char* ws = (char*)d_ws;
  unsigned char* Wq = (unsigned char*)ws;
  size_t off = (size_t)N_PAD * DKB;                // 51,511,296 B
  unsigned char* EqT = (unsigned char*)(ws + off);
  off += (size_t)B_ROWS * DKB;                     // + 2,097,152 B
  float* pm = (float*)(ws + off); off += (size_t)GN * B_ROWS * 4;
  float* ps = (float*)(ws + off); off += (size_t)GN * B_ROWS * 4;
  float* pt = (float*)(ws + off); off += (size_t)GN * B_ROWS * 4;
  float* ly = (float*)(ws + off);                  // total ~64 MB

  hipMemsetAsync(d_out, 0, sizeof(float), stream);
  conv_w_q4<<<dim3(2048), dim3(256), 0, stream>>>(W, Wq);
  conv_e_q4<<<dim3(512),  dim3(256), 0, stream>>>(E, EqT);
  gemm_ce<<<dim3(NWG), dim3(256), 0, stream>>>(EqT, Wq, labels, pm, ps, pt, ly);
  ce_reduce<<<dim3(B_ROWS / 256), dim3(256), 0, stream>>>(pm, ps, pt, ly, out);
}

// Round 19
// 395.758 us; speedup vs baseline: 1.1067x; 1.1067x over previous
//
#include <hip/hip_runtime.h>
#include <math.h>

#define B_ROWS 2048
#define D_K    2048
#define DKB    1024             // bytes per row at fp4 (0.5 B/elem)
#define N_CLS  50257
#define BM     128
#define BN     128
#define BKB    64               // K-BYTES per step = 128 elements
#define NT     16               // 2048 / 128 elements
#define GM     16               // 2048/128 m-tiles
#define GN     393              // ceil(50257/128) n-tiles
#define N_PAD  (GN * BN)        // 50304
#define NWG    (GM * GN)        // 6288 = 8*786 (bijective XCD swizzle)

// LDS: TRIPLE buffer, 16KB each (distance-2 prefetch, counted vmcnt(4)).
// Buffer b at b*16384: A [128 rows][64 B] at +0 (8KB), B at +8192 (8KB).
// 16-B slot swizzle within each 64-B row: position p = content_slot ^ ((row>>1)&3)
// (verified conflict-free R16/R17). Stats (3KB) overlay buf0 after the loop.
#define BBY    8192
#define BUFB   16384

typedef __attribute__((ext_vector_type(4))) int   i32x4;
typedef __attribute__((ext_vector_type(8))) int   i32x8;
typedef __attribute__((ext_vector_type(4))) float f32x4;

typedef __attribute__((address_space(1))) const void as1cv;
typedef __attribute__((address_space(3))) void       as3v;

__device__ __forceinline__ void glds16(const void* g, void* l) {
  __builtin_amdgcn_global_load_lds((as1cv*)g, (as3v*)l, 16, 0, 0);
}

// ---- fp32 -> fp4 e2m1 (RNE on the 8-level grid), returns 4-bit code ----
__device__ __forceinline__ unsigned int q4(float x) {
  const unsigned int s = (x < 0.f) ? 8u : 0u;
  const float a = fabsf(x);
  unsigned int c;
  if      (a < 0.25f) c = 0;
  else if (a < 0.75f) c = 1;
  else if (a < 1.25f) c = 2;
  else if (a < 1.75f) c = 3;
  else if (a < 2.5f)  c = 4;
  else if (a < 3.5f)  c = 5;
  else if (a < 5.0f)  c = 6;
  else                c = 7;
  return s | c;
}

// ---------- fused conversion: W (blocks 0..2047) + E (blocks 2048..2559) ----------
// Also zeroes out[0] (runs before ce_reduce in stream order) -> no memset node.
__global__ void conv_all(const float* __restrict__ W, const float* __restrict__ E,
                         unsigned char* __restrict__ Wq, unsigned char* __restrict__ Eq,
                         float* __restrict__ out) {
  if (blockIdx.x == 0 && threadIdx.x == 0) *out = 0.f;
  if (blockIdx.x < 2048) {
    // W: fp32 -> fp4, scaled x128, zero-padded to N_PAD rows.
    const size_t NU = (size_t)N_PAD * D_K / 16;
    const size_t stride = (size_t)2048 * 256;
    for (size_t u = (size_t)blockIdx.x * 256 + threadIdx.x; u < NU; u += stride) {
      const size_t e = u * 16;
      unsigned long long pk = 0ull;
      if ((e >> 11) < (size_t)N_CLS) {
#pragma unroll
        for (int g = 0; g < 4; ++g) {
          const float4 a = *(const float4*)(W + e + g * 4);
          pk |= (unsigned long long)q4(a.x * 128.0f) << (16 * g + 0);
          pk |= (unsigned long long)q4(a.y * 128.0f) << (16 * g + 4);
          pk |= (unsigned long long)q4(a.z * 128.0f) << (16 * g + 8);
          pk |= (unsigned long long)q4(a.w * 128.0f) << (16 * g + 12);
        }
      }
      *(unsigned long long*)(Wq + u * 8) = pk;
    }
  } else {
    // E: fp32 -> fp4, unscaled, row-major.
    const size_t NU = (size_t)B_ROWS * D_K / 16;
    const size_t stride = (size_t)512 * 256;
    for (size_t u = (size_t)(blockIdx.x - 2048) * 256 + threadIdx.x; u < NU; u += stride) {
      const size_t e = u * 16;
      unsigned long long pk = 0ull;
#pragma unroll
      for (int g = 0; g < 4; ++g) {
        const float4 a = *(const float4*)(E + e + g * 4);
        pk |= (unsigned long long)q4(a.x) << (16 * g + 0);
        pk |= (unsigned long long)q4(a.y) << (16 * g + 4);
        pk |= (unsigned long long)q4(a.z) << (16 * g + 8);
        pk |= (unsigned long long)q4(a.w) << (16 * g + 12);
      }
      *(unsigned long long*)(Eq + u * 8) = pk;
    }
  }
}

// ---------- fused MX-fp4 GEMM + per-tile row stats (R17 verbatim) ----------
// 128x128 tile, 4 waves (2x2), per-wave 64x64 via 4x4 mfma_scale 16x16x128 fp4.
// f32x4 acc[4][4] = the never-spilled profile. 3-buffer LDS, distance-2
// prefetch, counted vmcnt(4) across raw barriers.
__global__ __launch_bounds__(256) void gemm_ce(
    const unsigned char* __restrict__ Eq,
    const unsigned char* __restrict__ Wq,
    const int* __restrict__ labels,
    float* __restrict__ pm, float* __restrict__ ps, float* __restrict__ pt,
    float* __restrict__ ly)
{
  __shared__ __align__(16) char lds[3 * BUFB];
  // stats overlay (live only after the K-loop's final barrier):
  float (*s_m)[2] = (float (*)[2])(lds);
  float (*s_s)[2] = (float (*)[2])(lds + 1024);
  float (*s_t)[2] = (float (*)[2])(lds + 2048);

  const int tid  = threadIdx.x;
  const int wid  = tid >> 6;
  const int lane = tid & 63;
  const int wm   = wid >> 1;       // 0..1 -> 64-row block
  const int wn   = wid & 1;        // 0..1 -> 64-col block
  const int l16  = lane & 15;
  const int lhi  = lane >> 4;      // 0..3 -> 32-element k-chunk

  // XCD-aware bijective swizzle (NWG = 8*786)
  const int bid     = blockIdx.x;
  const int logical = (bid & 7) * (NWG / 8) + (bid >> 3);
  const int n_tile  = logical / GM;   // 16 consecutive logicals share B panel
  const int m_tile  = logical % GM;

  // ---- staging: thread t, part q -> dest byte q*4096 + t*16
  //      row = q*64 + (t>>2); slot position = t&3
  //      content slot = (t&3) ^ ((row>>1)&3) = (t&3) ^ ((t>>3)&3)
  const int gsw  = (((tid & 3) ^ ((tid >> 3) & 3)) << 4);
  const int srow = tid >> 2;
  const unsigned char* Ag = Eq + (size_t)(m_tile * BM + srow) * DKB + gsw;
  const unsigned char* Bg = Wq + (size_t)(n_tile * BN + srow) * DKB + gsw;
  const int sdst = tid * 16;
  // +q -> +64 rows = +65536 B global; +K-step -> +64 B

  // ---- fragment read offsets: row R = base + l16 (64-B rows), content slot
  //      = lhi, position = lhi ^ ((R>>1)&3) = lhi ^ ((l16>>1)&3)
  const int rmsk = (l16 >> 1) & 3;
  const int psw  = (lhi ^ rmsk) << 4;
  int offA[4], offB[4];
#pragma unroll
  for (int fi = 0; fi < 4; ++fi)
    offA[fi] = (wm * 64 + fi * 16 + l16) * 64 + psw;
#pragma unroll
  for (int fj = 0; fj < 4; ++fj)
    offB[fj] = BBY + (wn * 64 + fj * 16 + l16) * 64 + psw;

  f32x4 acc[4][4] = {};

#define STAGE(BUF, TT)                                                     \
  do {                                                                     \
    const unsigned char* _a = Ag + (size_t)(TT) * BKB;                     \
    const unsigned char* _b = Bg + (size_t)(TT) * BKB;                     \
    char* _d = lds + (BUF) * BUFB + sdst;                                  \
    glds16(_a,         _d);                                                \
    glds16(_a + 65536, _d + 4096);                                         \
    glds16(_b,         _d + BBY);                                          \
    glds16(_b + 65536, _d + BBY + 4096);                                   \
  } while (0)

  // prologue: stage tiles 0,1 into bufs 0,1; drain tile 0 only
  STAGE(0, 0);
  STAGE(1, 1);
  asm volatile("s_waitcnt vmcnt(4)" ::: "memory");
  __builtin_amdgcn_sched_barrier(0);
  __builtin_amdgcn_s_barrier();
  __builtin_amdgcn_sched_barrier(0);

  int c0 = 0, c1 = 1, c2 = 2;
  for (int t = 0; t < NT; ++t) {
    const char* Rb = lds + c0 * BUFB;

    if (t < NT - 2) STAGE(c2, t + 2);   // distance-2 prefetch

    i32x8 fa[4], fb[4];
#pragma unroll
    for (int fi = 0; fi < 4; ++fi) {
      const i32x4 v = *(const i32x4*)(Rb + offA[fi]);
      fa[fi][0] = v[0]; fa[fi][1] = v[1]; fa[fi][2] = v[2]; fa[fi][3] = v[3];
      fa[fi][4] = 0; fa[fi][5] = 0; fa[fi][6] = 0; fa[fi][7] = 0;
    }
#pragma unroll
    for (int fj = 0; fj < 4; ++fj) {
      const i32x4 v = *(const i32x4*)(Rb + offB[fj]);
      fb[fj][0] = v[0]; fb[fj][1] = v[1]; fb[fj][2] = v[2]; fb[fj][3] = v[3];
      fb[fj][4] = 0; fb[fj][5] = 0; fb[fj][6] = 0; fb[fj][7] = 0;
    }

    __builtin_amdgcn_s_setprio(1);
#pragma unroll
    for (int fi = 0; fi < 4; ++fi)
#pragma unroll
      for (int fj = 0; fj < 4; ++fj)
        acc[fi][fj] = __builtin_amdgcn_mfma_scale_f32_16x16x128_f8f6f4(
            fa[fi], fb[fj], acc[fi][fj], 4, 4,          // cbsz=4, blgp=4 (e2m1)
            0, 0x7F7F7F7F, 0, 0x7F7F7F7F);              // uniform scales = 1.0
    __builtin_amdgcn_s_setprio(0);

    // end of step: drain stage(t+1); keep stage(t+2) in flight.
    if (t < NT - 2) asm volatile("s_waitcnt vmcnt(4)" ::: "memory");
    else            asm volatile("s_waitcnt vmcnt(0)" ::: "memory");
    __builtin_amdgcn_sched_barrier(0);
    __builtin_amdgcn_s_barrier();
    __builtin_amdgcn_sched_barrier(0);

    const int tmp = c0; c0 = c1; c1 = c2; c2 = tmp;
  }
#undef STAGE

  // ---------- epilogue: per-row (max, sumexp, sum) + label gather ----------
  // C/D 16x16: col = lane&15, row = (lane>>4)*4 + reg  [verified R9/R10/R16]
  const float inv = 0.0078125f;   // 1/128 (undo W pre-scale)
  const int row_base = m_tile * BM;
  const int col_base = n_tile * BN + wn * 64;

#pragma unroll
  for (int fi = 0; fi < 4; ++fi) {
#pragma unroll
    for (int r = 0; r < 4; ++r) {
      const int rt  = wm * 64 + fi * 16 + lhi * 4 + r;
      const int row = row_base + rt;
      const int lab = labels[row];
      const int rel = lab - col_base - l16;
#pragma unroll
      for (int fj = 0; fj < 4; ++fj) {
        if (rel == fj * 16) ly[row] = acc[fi][fj][r] * inv;   // static acc index
      }

      float mx = -INFINITY, sm = 0.f;
#pragma unroll
      for (int fj = 0; fj < 4; ++fj) {
        const bool v = (col_base + fj * 16 + l16) < N_CLS;
        const float x = acc[fi][fj][r] * inv;
        if (v) { mx = fmaxf(mx, x); sm += x; }
      }
#pragma unroll
      for (int d = 1; d < 16; d <<= 1) {
        mx = fmaxf(mx, __shfl_xor(mx, d));
        sm += __shfl_xor(sm, d);
      }
      float se = 0.f;
#pragma unroll
      for (int fj = 0; fj < 4; ++fj) {
        const bool v = (col_base + fj * 16 + l16) < N_CLS;
        if (v) se += __expf(acc[fi][fj][r] * inv - mx);
      }
#pragma unroll
      for (int d = 1; d < 16; d <<= 1) se += __shfl_xor(se, d);

      if (l16 == 0) { s_m[rt][wn] = mx; s_s[rt][wn] = se; s_t[rt][wn] = sm; }
    }
  }
  __syncthreads();
  if (tid < BM) {
    const float m0 = s_m[tid][0], m1 = s_m[tid][1];
    const float M = fmaxf(m0, m1);
    const float S = s_s[tid][0] * __expf(m0 - M) + s_s[tid][1] * __expf(m1 - M);
    const float T = s_t[tid][0] + s_t[tid][1];
    const size_t o = (size_t)n_tile * B_ROWS + row_base + tid;
    pm[o] = M; ps[o] = S; pt[o] = T;
  }
}

// ---------- final combine: GN partials per row -> loss (16 blocks x 128) ----------
__global__ void ce_reduce(const float* __restrict__ pm, const float* __restrict__ ps,
                          const float* __restrict__ pt, const float* __restrict__ ly,
                          float* __restrict__ out)
{
  const int tid = threadIdx.x;
  const int row = blockIdx.x * 128 + tid;
  float M = -INFINITY, S = 0.f, T = 0.f;
  for (int nt = 0; nt < GN; ++nt) {
    const size_t o = (size_t)nt * B_ROWS + row;
    const float m = pm[o], s = ps[o], t = pt[o];
    const float Mn = fmaxf(M, m);
    S = S * __expf(M - Mn) + s * __expf(m - Mn);
    M = Mn;
    T += t;
  }
  const float lse = M + logf(S);
  float per = lse - 0.9f * ly[row] - 0.1f * (T * (1.0f / (float)N_CLS));
#pragma unroll
  for (int d = 1; d < 64; d <<= 1) per += __shfl_xor(per, d);
  __shared__ float red[2];
  if ((tid & 63) == 0) red[tid >> 6] = per;
  __syncthreads();
  if (tid == 0)
    atomicAdd(out, (red[0] + red[1]) * (1.0f / B_ROWS));
}

extern "C" void kernel_launch(void* const* d_in, const int* in_sizes, int n_in,
                              void* d_out, int out_size, void* d_ws, size_t ws_size,
                              hipStream_t stream)
{
  const float* E      = (const float*)d_in[0];
  const int*   labels = (const int*)  d_in[1];
  const float* W      = (const float*)d_in[2];
  float* out = (float*)d_out;

  char* ws = (char*)d_ws;
  unsigned char* Wq = (unsigned char*)ws;
  size_t off = (size_t)N_PAD * DKB;                // 51,511,296 B
  unsigned char* Eq = (unsigned char*)(ws + off);
  off += (size_t)B_ROWS * DKB;                     // + 2,097,152 B
  float* pm = (float*)(ws + off); off += (size_t)GN * B_ROWS * 4;
  float* ps = (float*)(ws + off); off += (size_t)GN * B_ROWS * 4;
  float* pt = (float*)(ws + off); off += (size_t)GN * B_ROWS * 4;
  float* ly = (float*)(ws + off);                  // total ~64 MB

  conv_all<<<dim3(2560), dim3(256), 0, stream>>>(W, E, Wq, Eq, out);
  gemm_ce<<<dim3(NWG), dim3(256), 0, stream>>>(Eq, Wq, labels, pm, ps, pt, ly);
  ce_reduce<<<dim3(16), dim3(128), 0, stream>>>(pm, ps, pt, ly, out);
}

// Round 20
// 395.292 us; speedup vs baseline: 1.1080x; 1.0012x over previous
//
#include <hip/hip_runtime.h>
#include <math.h>

#define B_ROWS 2048
#define D_K    2048
#define DKB    1024             // bytes per row at fp4 (0.5 B/elem)
#define N_CLS  50257
#define BM     128
#define BN     128
#define BKB    64               // K-BYTES per step = 128 elements
#define NT     16               // 2048 / 128 elements
#define GM     16               // 2048/128 m-tiles
#define GN     393              // ceil(50257/128) n-tiles
#define N_PAD  (GN * BN)        // 50304
#define NWG    (GM * GN)        // 6288 = 8*786 (bijective XCD swizzle)

// LDS: TRIPLE buffer, 16KB each (distance-2 prefetch, counted vmcnt(4)).
// Buffer b at b*16384: A [128 rows][64 B] at +0 (8KB), B at +8192 (8KB).
// 16-B slot swizzle within each 64-B row: position p = content_slot ^ ((row>>1)&3)
// (verified conflict-free R16/R17). Stats (3KB) overlay buf0 after the loop.
#define BBY    8192
#define BUFB   16384

typedef __attribute__((ext_vector_type(4))) int   i32x4;
typedef __attribute__((ext_vector_type(8))) int   i32x8;
typedef __attribute__((ext_vector_type(4))) float f32x4;

typedef __attribute__((address_space(1))) const void as1cv;
typedef __attribute__((address_space(3))) void       as3v;

__device__ __forceinline__ void glds16(const void* g, void* l) {
  __builtin_amdgcn_global_load_lds((as1cv*)g, (as3v*)l, 16, 0, 0);
}

// ---- fp32 -> fp4 e2m1 (RNE on the 8-level grid), returns 4-bit code ----
__device__ __forceinline__ unsigned int q4(float x) {
  const unsigned int s = (x < 0.f) ? 8u : 0u;
  const float a = fabsf(x);
  unsigned int c;
  if      (a < 0.25f) c = 0;
  else if (a < 0.75f) c = 1;
  else if (a < 1.25f) c = 2;
  else if (a < 1.75f) c = 3;
  else if (a < 2.5f)  c = 4;
  else if (a < 3.5f)  c = 5;
  else if (a < 5.0f)  c = 6;
  else                c = 7;
  return s | c;
}

// ---------- fused conversion: W (blocks 0..2047) + E (blocks 2048..2559) ----------
// Also zeroes out[0] (runs before ce_reduce in stream order) -> no memset node.
__global__ void conv_all(const float* __restrict__ W, const float* __restrict__ E,
                         unsigned char* __restrict__ Wq, unsigned char* __restrict__ Eq,
                         float* __restrict__ out) {
  if (blockIdx.x == 0 && threadIdx.x == 0) *out = 0.f;
  if (blockIdx.x < 2048) {
    // W: fp32 -> fp4, scaled x128, zero-padded to N_PAD rows.
    const size_t NU = (size_t)N_PAD * D_K / 16;
    const size_t stride = (size_t)2048 * 256;
    for (size_t u = (size_t)blockIdx.x * 256 + threadIdx.x; u < NU; u += stride) {
      const size_t e = u * 16;
      unsigned long long pk = 0ull;
      if ((e >> 11) < (size_t)N_CLS) {
#pragma unroll
        for (int g = 0; g < 4; ++g) {
          const float4 a = *(const float4*)(W + e + g * 4);
          pk |= (unsigned long long)q4(a.x * 128.0f) << (16 * g + 0);
          pk |= (unsigned long long)q4(a.y * 128.0f) << (16 * g + 4);
          pk |= (unsigned long long)q4(a.z * 128.0f) << (16 * g + 8);
          pk |= (unsigned long long)q4(a.w * 128.0f) << (16 * g + 12);
        }
      }
      *(unsigned long long*)(Wq + u * 8) = pk;
    }
  } else {
    // E: fp32 -> fp4, unscaled, row-major.
    const size_t NU = (size_t)B_ROWS * D_K / 16;
    const size_t stride = (size_t)512 * 256;
    for (size_t u = (size_t)(blockIdx.x - 2048) * 256 + threadIdx.x; u < NU; u += stride) {
      const size_t e = u * 16;
      unsigned long long pk = 0ull;
#pragma unroll
      for (int g = 0; g < 4; ++g) {
        const float4 a = *(const float4*)(E + e + g * 4);
        pk |= (unsigned long long)q4(a.x) << (16 * g + 0);
        pk |= (unsigned long long)q4(a.y) << (16 * g + 4);
        pk |= (unsigned long long)q4(a.z) << (16 * g + 8);
        pk |= (unsigned long long)q4(a.w) << (16 * g + 12);
      }
      *(unsigned long long*)(Eq + u * 8) = pk;
    }
  }
}

// ---------- fused MX-fp4 GEMM + per-tile row stats ----------
// 128x128 tile, 4 waves (2x2), per-wave 64x64 via 4x4 mfma_scale 16x16x128 fp4.
// f32x4 acc[4][4] = the never-spilled profile. 3-buffer LDS, distance-2
// prefetch, counted vmcnt(4) across raw barriers. K-loop FULLY UNROLLED with
// static (t%3) buffer indices: all LDS offsets fold to immediates.
__global__ __launch_bounds__(256) void gemm_ce(
    const unsigned char* __restrict__ Eq,
    const unsigned char* __restrict__ Wq,
    const int* __restrict__ labels,
    float* __restrict__ pm, float* __restrict__ ps, float* __restrict__ pt,
    float* __restrict__ ly)
{
  __shared__ __align__(16) char lds[3 * BUFB];
  // stats overlay (live only after the K-loop's final barrier):
  float (*s_m)[2] = (float (*)[2])(lds);
  float (*s_s)[2] = (float (*)[2])(lds + 1024);
  float (*s_t)[2] = (float (*)[2])(lds + 2048);

  const int tid  = threadIdx.x;
  const int wid  = tid >> 6;
  const int lane = tid & 63;
  const int wm   = wid >> 1;       // 0..1 -> 64-row block
  const int wn   = wid & 1;        // 0..1 -> 64-col block
  const int l16  = lane & 15;
  const int lhi  = lane >> 4;      // 0..3 -> 32-element k-chunk

  // XCD-aware bijective swizzle (NWG = 8*786)
  const int bid     = blockIdx.x;
  const int logical = (bid & 7) * (NWG / 8) + (bid >> 3);
  const int n_tile  = logical / GM;   // 16 consecutive logicals share B panel
  const int m_tile  = logical % GM;

  // ---- staging: thread t, part q -> dest byte q*4096 + t*16
  //      row = q*64 + (t>>2); slot position = t&3
  //      content slot = (t&3) ^ ((row>>1)&3) = (t&3) ^ ((t>>3)&3)
  const int gsw  = (((tid & 3) ^ ((tid >> 3) & 3)) << 4);
  const int srow = tid >> 2;
  const unsigned char* Ag = Eq + (size_t)(m_tile * BM + srow) * DKB + gsw;
  const unsigned char* Bg = Wq + (size_t)(n_tile * BN + srow) * DKB + gsw;
  const int sdst = tid * 16;
  // +q -> +64 rows = +65536 B global; +K-step -> +64 B

  // ---- fragment read offsets: row R = base + l16 (64-B rows), content slot
  //      = lhi, position = lhi ^ ((R>>1)&3) = lhi ^ ((l16>>1)&3)
  const int rmsk = (l16 >> 1) & 3;
  const int psw  = (lhi ^ rmsk) << 4;
  int offA[4], offB[4];
#pragma unroll
  for (int fi = 0; fi < 4; ++fi)
    offA[fi] = (wm * 64 + fi * 16 + l16) * 64 + psw;
#pragma unroll
  for (int fj = 0; fj < 4; ++fj)
    offB[fj] = BBY + (wn * 64 + fj * 16 + l16) * 64 + psw;

  f32x4 acc[4][4] = {};

#define STAGE(BUF, TT)                                                     \
  do {                                                                     \
    const unsigned char* _a = Ag + (size_t)(TT) * BKB;                     \
    const unsigned char* _b = Bg + (size_t)(TT) * BKB;                     \
    char* _d = lds + (BUF) * BUFB + sdst;                                  \
    glds16(_a,         _d);                                                \
    glds16(_a + 65536, _d + 4096);                                         \
    glds16(_b,         _d + BBY);                                          \
    glds16(_b + 65536, _d + BBY + 4096);                                   \
  } while (0)

  // prologue: stage tiles 0,1 into bufs 0,1; drain tile 0 only
  STAGE(0, 0);
  STAGE(1, 1);
  asm volatile("s_waitcnt vmcnt(4)" ::: "memory");
  __builtin_amdgcn_sched_barrier(0);
  __builtin_amdgcn_s_barrier();
  __builtin_amdgcn_sched_barrier(0);

#pragma unroll
  for (int t = 0; t < NT; ++t) {
    const char* Rb = lds + (t % 3) * BUFB;      // static per unrolled iteration

    if (t < NT - 2) STAGE((t + 2) % 3, t + 2);  // distance-2 prefetch

    i32x8 fa[4], fb[4];
#pragma unroll
    for (int fi = 0; fi < 4; ++fi) {
      const i32x4 v = *(const i32x4*)(Rb + offA[fi]);
      fa[fi][0] = v[0]; fa[fi][1] = v[1]; fa[fi][2] = v[2]; fa[fi][3] = v[3];
      fa[fi][4] = 0; fa[fi][5] = 0; fa[fi][6] = 0; fa[fi][7] = 0;
    }
#pragma unroll
    for (int fj = 0; fj < 4; ++fj) {
      const i32x4 v = *(const i32x4*)(Rb + offB[fj]);
      fb[fj][0] = v[0]; fb[fj][1] = v[1]; fb[fj][2] = v[2]; fb[fj][3] = v[3];
      fb[fj][4] = 0; fb[fj][5] = 0; fb[fj][6] = 0; fb[fj][7] = 0;
    }

    __builtin_amdgcn_s_setprio(1);
#pragma unroll
    for (int fi = 0; fi < 4; ++fi)
#pragma unroll
      for (int fj = 0; fj < 4; ++fj)
        acc[fi][fj] = __builtin_amdgcn_mfma_scale_f32_16x16x128_f8f6f4(
            fa[fi], fb[fj], acc[fi][fj], 4, 4,          // cbsz=4, blgp=4 (e2m1)
            0, 0x7F7F7F7F, 0, 0x7F7F7F7F);              // uniform scales = 1.0
    __builtin_amdgcn_s_setprio(0);

    // end of step: drain stage(t+1); keep stage(t+2) in flight.
    if (t < NT - 2) asm volatile("s_waitcnt vmcnt(4)" ::: "memory");
    else            asm volatile("s_waitcnt vmcnt(0)" ::: "memory");
    __builtin_amdgcn_sched_barrier(0);
    __builtin_amdgcn_s_barrier();
    __builtin_amdgcn_sched_barrier(0);
  }
#undef STAGE

  // ---------- epilogue: per-row (max, sumexp, sum) + label gather ----------
  // C/D 16x16: col = lane&15, row = (lane>>4)*4 + reg  [verified R9/R10/R16]
  const float inv = 0.0078125f;   // 1/128 (undo W pre-scale)
  const int row_base = m_tile * BM;
  const int col_base = n_tile * BN + wn * 64;

#pragma unroll
  for (int fi = 0; fi < 4; ++fi) {
#pragma unroll
    for (int r = 0; r < 4; ++r) {
      const int rt  = wm * 64 + fi * 16 + lhi * 4 + r;
      const int row = row_base + rt;
      const int lab = labels[row];
      const int rel = lab - col_base - l16;
#pragma unroll
      for (int fj = 0; fj < 4; ++fj) {
        if (rel == fj * 16) ly[row] = acc[fi][fj][r] * inv;   // static acc index
      }

      float mx = -INFINITY, sm = 0.f;
#pragma unroll
      for (int fj = 0; fj < 4; ++fj) {
        const bool v = (col_base + fj * 16 + l16) < N_CLS;
        const float x = acc[fi][fj][r] * inv;
        if (v) { mx = fmaxf(mx, x); sm += x; }
      }
#pragma unroll
      for (int d = 1; d < 16; d <<= 1) {
        mx = fmaxf(mx, __shfl_xor(mx, d));
        sm += __shfl_xor(sm, d);
      }
      float se = 0.f;
#pragma unroll
      for (int fj = 0; fj < 4; ++fj) {
        const bool v = (col_base + fj * 16 + l16) < N_CLS;
        if (v) se += __expf(acc[fi][fj][r] * inv - mx);
      }
#pragma unroll
      for (int d = 1; d < 16; d <<= 1) se += __shfl_xor(se, d);

      if (l16 == 0) { s_m[rt][wn] = mx; s_s[rt][wn] = se; s_t[rt][wn] = sm; }
    }
  }
  __syncthreads();
  if (tid < BM) {
    const float m0 = s_m[tid][0], m1 = s_m[tid][1];
    const float M = fmaxf(m0, m1);
    const float S = s_s[tid][0] * __expf(m0 - M) + s_s[tid][1] * __expf(m1 - M);
    const float T = s_t[tid][0] + s_t[tid][1];
    const size_t o = (size_t)n_tile * B_ROWS + row_base + tid;
    pm[o] = M; ps[o] = S; pt[o] = T;
  }
}

// ---------- final combine: GN partials per row -> loss (16 blocks x 128) ----------
__global__ void ce_reduce(const float* __restrict__ pm, const float* __restrict__ ps,
                          const float* __restrict__ pt, const float* __restrict__ ly,
                          float* __restrict__ out)
{
  const int tid = threadIdx.x;
  const int row = blockIdx.x * 128 + tid;
  float M = -INFINITY, S = 0.f, T = 0.f;
  for (int nt = 0; nt < GN; ++nt) {
    const size_t o = (size_t)nt * B_ROWS + row;
    const float m = pm[o], s = ps[o], t = pt[o];
    const float Mn = fmaxf(M, m);
    S = S * __expf(M - Mn) + s * __expf(m - Mn);
    M = Mn;
    T += t;
  }
  const float lse = M + logf(S);
  float per = lse - 0.9f * ly[row] - 0.1f * (T * (1.0f / (float)N_CLS));
#pragma unroll
  for (int d = 1; d < 64; d <<= 1) per += __shfl_xor(per, d);
  __shared__ float red[2];
  if ((tid & 63) == 0) red[tid >> 6] = per;
  __syncthreads();
  if (tid == 0)
    atomicAdd(out, (red[0] + red[1]) * (1.0f / B_ROWS));
}

extern "C" void kernel_launch(void* const* d_in, const int* in_sizes, int n_in,
                              void* d_out, int out_size, void* d_ws, size_t ws_size,
                              hipStream_t stream)
{
  const float* E      = (const float*)d_in[0];
  const int*   labels = (const int*)  d_in[1];
  const float* W      = (const float*)d_in[2];
  float* out = (float*)d_out;

  char* ws = (char*)d_ws;
  unsigned char* Wq = (unsigned char*)ws;
  size_t off = (size_t)N_PAD * DKB;                // 51,511,296 B
  unsigned char* Eq = (unsigned char*)(ws + off);
  off += (size_t)B_ROWS * DKB;                     // + 2,097,152 B
  float* pm = (float*)(ws + off); off += (size_t)GN * B_ROWS * 4;
  float* ps = (float*)(ws + off); off += (size_t)GN * B_ROWS * 4;
  float* pt = (float*)(ws + off); off += (size_t)GN * B_ROWS * 4;
  float* ly = (float*)(ws + off);                  // total ~64 MB

  conv_all<<<dim3(2560), dim3(256), 0, stream>>>(W, E, Wq, Eq, out);
  gemm_ce<<<dim3(NWG), dim3(256), 0, stream>>>(Eq, Wq, labels, pm, ps, pt, ly);
  ce_reduce<<<dim3(16), dim3(128), 0, stream>>>(pm, ps, pt, ly, out);
}